// Round 2
// baseline (291.053 us; speedup 1.0000x reference)
//
#include <hip/hip_runtime.h>

#define N_   16
#define C_   512
#define GRP  4
#define CG   128
#define MIP  16

__device__ __forceinline__ float bf_lo(unsigned u) { return __uint_as_float(u << 16); }
__device__ __forceinline__ float bf_hi(unsigned u) { return __uint_as_float(u & 0xFFFF0000u); }
__device__ __forceinline__ float bf1(unsigned short s) { return __uint_as_float((unsigned)s << 16); }

__device__ __forceinline__ float ld_scalar(const void* p, int i, bool isbf) {
    return isbf ? bf1(((const unsigned short*)p)[i]) : ((const float*)p)[i];
}

// Per-block dtype sniff on x[0..255] words (same 1 KB for every block, L2-hot).
__device__ __forceinline__ bool sniff_isbf(const unsigned* __restrict__ x32,
                                           int t, unsigned* s_flag) {
    if (t < 64) {
        int cnt = 0;
        #pragma unroll
        for (int k = 0; k < 4; ++k) {
            unsigned w = x32[t + 64 * k];
            unsigned e = (w >> 7) & 0xFFu;
            cnt += (e >= 0x60u && e <= 0x9Fu) ? 1 : 0;
        }
        #pragma unroll
        for (int off = 32; off > 0; off >>= 1) cnt += __shfl_down(cnt, off, 64);
        if (t == 0) *s_flag = (cnt >= 192) ? 1u : 0u;
    }
    __syncthreads();
    return *s_flag != 0u;
}

// ---------------------------------------------------------------------------
// K1: per-(n,ch) 64x64 tile -> row means (gh) and col means (gw).
// Register partials + shuffle row-reduce; 8.3 KB scratch for col partials.
// grid = 8192 blocks, 256 threads.
// ---------------------------------------------------------------------------
__global__ __launch_bounds__(256) void kreduce(const void* __restrict__ xv,
                                               float* __restrict__ gh,
                                               float* __restrict__ gw) {
    __shared__ float scratch[32][65];
    __shared__ unsigned flag_s;
    const int bid = blockIdx.x;            // n*512 + ch
    const int t = threadIdx.x;
    const bool isbf = sniff_isbf((const unsigned*)xv, t, &flag_s);

    if (isbf) {
        const uint4* src = (const uint4*)((const unsigned short*)xv + (size_t)bid * 4096);
        float cp[8] = {0,0,0,0,0,0,0,0};
        #pragma unroll
        for (int hf = 0; hf < 2; ++hf) {
            int idx = t + hf * 256;        // 8 bf16 per uint4; 8 uint4 per row
            int r = idx >> 3;
            uint4 v = src[idx];
            unsigned uu[4] = {v.x, v.y, v.z, v.w};
            float rp = 0.f;
            #pragma unroll
            for (int k = 0; k < 4; ++k) {
                float f0 = bf_lo(uu[k]), f1 = bf_hi(uu[k]);
                rp += f0 + f1;
                cp[2*k] += f0; cp[2*k+1] += f1;
            }
            rp += __shfl_xor(rp, 1);       // 8 lanes share a row
            rp += __shfl_xor(rp, 2);
            rp += __shfl_xor(rp, 4);
            if ((t & 7) == 0) gh[(size_t)bid * 64 + r] = rp * (1.f/64.f);
        }
        #pragma unroll
        for (int k = 0; k < 8; ++k) scratch[t >> 3][(t & 7) * 8 + k] = cp[k];
    } else {
        const float4* src = (const float4*)((const float*)xv + (size_t)bid * 4096);
        float cp[4] = {0,0,0,0};
        #pragma unroll
        for (int it = 0; it < 4; ++it) {
            int idx = t + it * 256;        // 4 fp32 per float4; 16 per row
            int r = idx >> 4;
            float4 v = src[idx];
            float rp = (v.x + v.y) + (v.z + v.w);
            cp[0] += v.x; cp[1] += v.y; cp[2] += v.z; cp[3] += v.w;
            rp += __shfl_xor(rp, 1);       // 16 lanes share a row
            rp += __shfl_xor(rp, 2);
            rp += __shfl_xor(rp, 4);
            rp += __shfl_xor(rp, 8);
            if ((t & 15) == 0) gh[(size_t)bid * 64 + r] = rp * (1.f/64.f);
        }
        #pragma unroll
        for (int k = 0; k < 4; ++k) scratch[t >> 4][(t & 15) * 4 + k] = cp[k];
    }
    __syncthreads();
    if (t < 64) {                          // final col reduce -> gw
        const int nr = isbf ? 32 : 16;
        float s = 0.f;
        for (int i = 0; i < nr; ++i) s += scratch[i][t];
        gw[(size_t)bid * 64 + t] = s * (1.f/64.f);
    }
}

// ---------------------------------------------------------------------------
// K2: per (n,g): y = hswish(BN(W1@[gh|gw]+b1)) kept in LDS, then the FULL
// attention maps A_h/A_w = sigmoid(W@y + b) written to global (4 MB fp32).
// grid = 64 blocks, 256 threads.
// ---------------------------------------------------------------------------
__global__ __launch_bounds__(256) void kmid(
    const void* __restrict__ xv,
    const float* __restrict__ gh, const float* __restrict__ gw,
    const void* __restrict__ W1, const void* __restrict__ b1,
    const void* __restrict__ gamma, const void* __restrict__ beta,
    const void* __restrict__ mean, const void* __restrict__ var,
    const void* __restrict__ Wh, const void* __restrict__ bh,
    const void* __restrict__ Ww, const void* __restrict__ bw,
    float* __restrict__ aH, float* __restrict__ aW)
{
    __shared__ float W1_s[MIP * CG];       // [m][cc]
    __shared__ float Whw_s[2][CG * MIP];   // [hf][cc][m]
    __shared__ float y_s[MIP * 128];       // [m][l]
    __shared__ float bhw_s[2][CG];
    __shared__ float scale_s[MIP], shift_s[MIP], b1_s[MIP];
    __shared__ unsigned flag_s;

    const int t = threadIdx.x;
    const int ng = blockIdx.x;             // n*4 + g
    const bool isbf = sniff_isbf((const unsigned*)xv, t, &flag_s);

    // ---- stage weights ----
    if (isbf) {
        uint4 v = ((const uint4*)W1)[t];   // 2048 bf16 = 256 uint4
        unsigned uu[4] = {v.x, v.y, v.z, v.w};
        #pragma unroll
        for (int k = 0; k < 4; ++k) {
            W1_s[t*8 + 2*k]   = bf_lo(uu[k]);
            W1_s[t*8 + 2*k+1] = bf_hi(uu[k]);
        }
        uint4 a = ((const uint4*)Wh)[t];
        unsigned ua[4] = {a.x, a.y, a.z, a.w};
        #pragma unroll
        for (int k = 0; k < 4; ++k) {
            Whw_s[0][t*8 + 2*k]   = bf_lo(ua[k]);
            Whw_s[0][t*8 + 2*k+1] = bf_hi(ua[k]);
        }
        uint4 c = ((const uint4*)Ww)[t];
        unsigned uc[4] = {c.x, c.y, c.z, c.w};
        #pragma unroll
        for (int k = 0; k < 4; ++k) {
            Whw_s[1][t*8 + 2*k]   = bf_lo(uc[k]);
            Whw_s[1][t*8 + 2*k+1] = bf_hi(uc[k]);
        }
    } else {
        #pragma unroll
        for (int it = 0; it < 2; ++it) {
            int idx = t + 256 * it;        // 2048 fp32 = 512 float4
            float4 v = ((const float4*)W1)[idx];
            W1_s[idx*4] = v.x; W1_s[idx*4+1] = v.y; W1_s[idx*4+2] = v.z; W1_s[idx*4+3] = v.w;
            float4 a = ((const float4*)Wh)[idx];
            Whw_s[0][idx*4] = a.x; Whw_s[0][idx*4+1] = a.y; Whw_s[0][idx*4+2] = a.z; Whw_s[0][idx*4+3] = a.w;
            float4 c = ((const float4*)Ww)[idx];
            Whw_s[1][idx*4] = c.x; Whw_s[1][idx*4+1] = c.y; Whw_s[1][idx*4+2] = c.z; Whw_s[1][idx*4+3] = c.w;
        }
    }
    if (t < CG) bhw_s[0][t] = ld_scalar(bh, t, isbf);
    else        bhw_s[1][t - CG] = ld_scalar(bw, t - CG, isbf);
    if (t < MIP) {
        float sc = ld_scalar(gamma, t, isbf) * rsqrtf(ld_scalar(var, t, isbf) + 1e-5f);
        scale_s[t] = sc;
        shift_s[t] = ld_scalar(beta, t, isbf) - ld_scalar(mean, t, isbf) * sc;
        b1_s[t] = ld_scalar(b1, t, isbf);
    }
    __syncthreads();

    // ---- y phase: y[m][l], l = t&127, m in [half*8, half*8+8) ----
    {
        const int l = t & 127;
        const int half = t >> 7;
        const float* gbase = (l < 64) ? (gh + (size_t)ng * 8192 + l)
                                      : (gw + (size_t)ng * 8192 + (l - 64));
        float acc[8] = {0,0,0,0,0,0,0,0};
        for (int cc = 0; cc < CG; ++cc) {
            float v = gbase[(size_t)cc * 64];
            #pragma unroll
            for (int mm = 0; mm < 8; ++mm)
                acc[mm] += W1_s[(half*8 + mm) * CG + cc] * v;
        }
        #pragma unroll
        for (int mm = 0; mm < 8; ++mm) {
            int m = half*8 + mm;
            float yv = acc[mm] + b1_s[m];
            yv = yv * scale_s[m] + shift_s[m];
            float hc = fminf(fmaxf(yv + 3.f, 0.f), 6.f);
            y_s[m * 128 + l] = yv * hc * (1.f/6.f);
        }
    }
    __syncthreads();

    // ---- A phase: 16384 outputs (hf,cc,i), 64 per thread ----
    for (int k = 0; k < 64; ++k) {
        int out = t + 256 * k;             // wave-uniform (hf,cc), i = lane
        int hf = out >> 13;
        int rem = out & 8191;
        int cc = rem >> 6;
        int i = rem & 63;
        float acc = bhw_s[hf][cc];
        #pragma unroll
        for (int m = 0; m < MIP; ++m)
            acc += Whw_s[hf][cc * MIP + m] * y_s[m * 128 + hf * 64 + i];
        float s = 1.f / (1.f + __expf(-acc));
        float* dst = hf ? aW : aH;
        dst[(size_t)ng * 8192 + cc * 64 + i] = s;
    }
}

// ---------------------------------------------------------------------------
// K3: pure streaming gate: out[n,o] = x[n,p] * a_h[r] * a_w[j]
// grid = 8192 blocks, 256 threads.
// ---------------------------------------------------------------------------
__global__ __launch_bounds__(256) void kapply(const void* __restrict__ xv,
                                              const float* __restrict__ aH,
                                              const float* __restrict__ aW,
                                              void* __restrict__ outv) {
    __shared__ float ah_s[64], aw_s[64];
    __shared__ unsigned flag_s;
    const int bid = blockIdx.x;            // n*512 + o
    const int n = bid >> 9;
    const int o = bid & 511;
    const int p = (o & 127) * 4 + (o >> 7);    // channel shuffle: input channel
    const int g = p >> 7, cc = p & 127;
    const int t = threadIdx.x;
    const bool isbf = sniff_isbf((const unsigned*)xv, t, &flag_s);
    const size_t abase = (size_t)(n * 4 + g) * 8192 + (size_t)cc * 64;

    if (isbf) {
        const uint4* src = (const uint4*)((const unsigned short*)xv + ((size_t)n * 512 + p) * 4096);
        uint4 x0 = src[t];                 // issue x loads first
        uint4 x1 = src[t + 256];
        if (t < 64)       ah_s[t]      = aH[abase + t];
        else if (t < 128) aw_s[t - 64] = aW[abase + (t - 64)];
        __syncthreads();
        uint4* dst = (uint4*)((unsigned short*)outv + (size_t)bid * 4096);
        uint4 xr[2] = {x0, x1};
        #pragma unroll
        for (int hf = 0; hf < 2; ++hf) {
            int idx = t + hf * 256;
            int r = idx >> 3, j0 = (idx & 7) * 8;
            float sah = ah_s[r];
            unsigned uu[4] = {xr[hf].x, xr[hf].y, xr[hf].z, xr[hf].w};
            unsigned res[4];
            #pragma unroll
            for (int k = 0; k < 4; ++k) {
                int j = j0 + 2 * k;
                float f0 = bf_lo(uu[k]) * sah * aw_s[j];
                float f1 = bf_hi(uu[k]) * sah * aw_s[j + 1];
                unsigned u0 = __float_as_uint(f0); u0 += 0x7FFFu + ((u0 >> 16) & 1u);
                unsigned u1 = __float_as_uint(f1); u1 += 0x7FFFu + ((u1 >> 16) & 1u);
                res[k] = (u0 >> 16) | (u1 & 0xFFFF0000u);
            }
            uint4 w2; w2.x = res[0]; w2.y = res[1]; w2.z = res[2]; w2.w = res[3];
            dst[idx] = w2;
        }
    } else {
        const float4* src = (const float4*)((const float*)xv + ((size_t)n * 512 + p) * 4096);
        float4 x0 = src[t];
        float4 x1 = src[t + 256];
        float4 x2 = src[t + 512];
        float4 x3 = src[t + 768];
        if (t < 64)       ah_s[t]      = aH[abase + t];
        else if (t < 128) aw_s[t - 64] = aW[abase + (t - 64)];
        __syncthreads();
        float4* dst = (float4*)((float*)outv + (size_t)bid * 4096);
        float4 xr[4] = {x0, x1, x2, x3};
        #pragma unroll
        for (int it = 0; it < 4; ++it) {
            int idx = t + it * 256;
            int r = idx >> 4, j0 = (idx & 15) * 4;
            float sah = ah_s[r];
            float4 v = xr[it];
            v.x *= sah * aw_s[j0];
            v.y *= sah * aw_s[j0 + 1];
            v.z *= sah * aw_s[j0 + 2];
            v.w *= sah * aw_s[j0 + 3];
            dst[idx] = v;
        }
    }
}

extern "C" void kernel_launch(void* const* d_in, const int* in_sizes, int n_in,
                              void* d_out, int out_size, void* d_ws, size_t ws_size,
                              hipStream_t stream) {
    const void* x     = d_in[0];
    const void* W1    = d_in[1];
    const void* b1    = d_in[2];
    const void* gamma = d_in[3];
    const void* beta  = d_in[4];
    const void* mean  = d_in[5];
    const void* var   = d_in[6];
    const void* Wh    = d_in[7];
    const void* bh    = d_in[8];
    const void* Ww    = d_in[9];
    const void* bw    = d_in[10];

    float* ws = (float*)d_ws;
    float* gh = ws;                    // 524288 floats (2 MB)
    float* gw = gh + 524288;           // 524288 floats
    float* aH = gw + 524288;           // 524288 floats
    float* aW = aH + 524288;           // 524288 floats

    kreduce<<<N_ * C_, 256, 0, stream>>>(x, gh, gw);
    kmid<<<N_ * GRP, 256, 0, stream>>>(x, gh, gw, W1, b1, gamma, beta, mean, var,
                                       Wh, bh, Ww, bw, aH, aW);
    kapply<<<N_ * C_, 256, 0, stream>>>(x, aH, aW, d_out);
}